// Round 4
// baseline (3379.549 us; speedup 1.0000x reference)
//
#include <hip/hip_runtime.h>
#include <hip/hip_bf16.h>

// GaussianLSTM: x(4,512,256) -> 2-layer LSTM(H=256) -> Gaussian head.
// Outputs concat: sample (524288) | mu (524288) | std_full (134217728) f32.
//
// Round 4: single-CU-per-layer-GEMV, LDS/barrier recurrence, one-way streams.
//   WG0: layer-0 recurrence. W_hh0 per wave: 10 reg-tiles + 4 LDS + 2 L2-hot.
//        h exchange via LDS (s_barrier). Publishes h0 as tagged 8B words.
//   WG1: xw1(t) = bias1 + W_ih1 @ h0(t)  (no recurrence; trails WG0).
//        Publishes tagged f32 words.
//   WG2: layer-1 recurrence with W_hh1; consumes xw1 stream; writes hs1.
//   Tags = t+1 in the same 8B atomic word as payload -> no fences, no tokens,
//   no ack on the serial chain. Streams are one-way (constant offset).
//   Replay-safe: all pub/scratch in std_full region, rewritten by finalize.

#define HD 256
#define SEQ 512

typedef __attribute__((ext_vector_type(8))) short short8;
typedef __attribute__((ext_vector_type(4))) float f32x4;
using u16 = unsigned short;
using u32 = unsigned int;
using u64 = unsigned long long;

#define MFMA16(a, bm, c) __builtin_amdgcn_mfma_f32_16x16x32_bf16((a), (bm), (c), 0, 0, 0)

__device__ inline u16 f2bf(float x) {
  u32 u = __float_as_uint(x);
  u32 r = (u + 0x7FFFu + ((u >> 16) & 1u)) >> 16;
  return (u16)r;
}

__device__ inline float fast_sigmoid(float z) { return 1.0f / (1.0f + __expf(-z)); }
__device__ inline float fast_tanh(float z) { return 1.0f - 2.0f / (1.0f + __expf(2.0f * z)); }

// ---------------- prep: pack W_hh0/W_ih1/W_hh1 into bf16 MFMA-frag layout ----
// pk[mat][ti][kk][l][j]: ti = w*16+p*4+m (w:wave 0..3, p:pass 0..3, m:gate),
// row = m*256 + w*64 + p*16 + (l&15), k = kk*32 + (l>>4)*8 + j.
__global__ __launch_bounds__(256) void prep_pack(
    const float* __restrict__ whh0, const float* __restrict__ wih1,
    const float* __restrict__ whh1, const float* __restrict__ bi1,
    const float* __restrict__ bh1, u16* __restrict__ pk,
    float* __restrict__ bias1s) {
  const int idx = blockIdx.x * 256 + threadIdx.x;
  if (idx < 786432) {
    const int mat = idx >> 18;
    const int e = idx & 262143;
    const int ti = e >> 12, r2 = e & 4095;
    const int kk = r2 >> 9, ll = (r2 >> 3) & 63, j = r2 & 7;
    const int w = ti >> 4, p = (ti >> 2) & 3, m = ti & 3;
    const int row = m * 256 + w * 64 + p * 16 + (ll & 15);
    const int k = kk * 32 + (ll >> 4) * 8 + j;
    const float* src = (mat == 0) ? whh0 : (mat == 1) ? wih1 : whh1;
    pk[idx] = f2bf(src[(size_t)row * 256 + k]);
  } else {
    const int i = idx - 786432;
    if (i < 1024) bias1s[i] = bi1[i] + bh1[i];
  }
}

// ------------------------------------------------- xw = in @ w^T + (ba+bb)
__global__ __launch_bounds__(256) void xw_gemm(
    const float* __restrict__ xin, const float* __restrict__ w,
    const float* __restrict__ ba, const float* __restrict__ bb,
    float* __restrict__ xw) {
  __shared__ float xs[4][HD];
  const int blk = blockIdx.x, tid = threadIdx.x;
  const int row0 = blk * 4;
  for (int i = tid; i < 4 * HD; i += 256) xs[i >> 8][i & 255] = xin[(size_t)row0 * HD + i];
  __syncthreads();
  float acc[4][4];
#pragma unroll
  for (int g = 0; g < 4; ++g)
#pragma unroll
    for (int tt = 0; tt < 4; ++tt) acc[g][tt] = 0.f;
#pragma unroll 2
  for (int kc = 0; kc < 64; ++kc) {
#pragma unroll
    for (int g = 0; g < 4; ++g) {
      const int r = g * HD + tid;
      const float4 wv = ((const float4*)(w + (size_t)r * HD))[kc];
#pragma unroll
      for (int tt = 0; tt < 4; ++tt) {
        const float4 hv = ((const float4*)xs[tt])[kc];
        acc[g][tt] += wv.x * hv.x + wv.y * hv.y + wv.z * hv.z + wv.w * hv.w;
      }
    }
  }
#pragma unroll
  for (int g = 0; g < 4; ++g) {
    const int r = g * HD + tid;
    const float bias = ba[r] + bb[r];
#pragma unroll
    for (int tt = 0; tt < 4; ++tt)
      xw[(size_t)(row0 + tt) * 1024 + r] = acc[g][tt] + bias;
  }
}

// ---------------- shared MFMA pass: acc[m] += Wtile(Q,m) @ h --------------
template <int Q>
__device__ __forceinline__ void pass_mfma(
    const short8 (&wf)[10][8], const short8 (&gA)[8], const short8 (&gB)[8],
    const u16* hrow, const u16* lw0, int l, f32x4 (&acc)[4]) {
  const int G8 = (l >> 4) * 8;
#pragma unroll
  for (int kk = 0; kk < 8; ++kk) {
    const short8 bfr = *(const short8*)(hrow + kk * 32 + G8);
    if (Q <= 1) {
      acc[0] = MFMA16(wf[Q * 4 + 0][kk], bfr, acc[0]);
      acc[1] = MFMA16(wf[Q * 4 + 1][kk], bfr, acc[1]);
      acc[2] = MFMA16(wf[Q * 4 + 2][kk], bfr, acc[2]);
      acc[3] = MFMA16(wf[Q * 4 + 3][kk], bfr, acc[3]);
    } else if (Q == 2) {
      acc[0] = MFMA16(wf[8][kk], bfr, acc[0]);
      acc[1] = MFMA16(wf[9][kk], bfr, acc[1]);
      acc[2] = MFMA16(*(const short8*)(lw0 + 0 * 4096 + kk * 512 + l * 8), bfr, acc[2]);
      acc[3] = MFMA16(*(const short8*)(lw0 + 1 * 4096 + kk * 512 + l * 8), bfr, acc[3]);
    } else {
      acc[0] = MFMA16(*(const short8*)(lw0 + 2 * 4096 + kk * 512 + l * 8), bfr, acc[0]);
      acc[1] = MFMA16(*(const short8*)(lw0 + 3 * 4096 + kk * 512 + l * 8), bfr, acc[1]);
      acc[2] = MFMA16(gA[kk], bfr, acc[2]);
      acc[3] = MFMA16(gB[kk], bfr, acc[3]);
    }
  }
}

__device__ __forceinline__ void gates4(const f32x4 (&acc)[4], const f32x4 (&xq)[4],
                                       f32x4& cq, f32x4& h) {
#pragma unroll
  for (int r = 0; r < 4; ++r) {
    const float zi = acc[0][r] + xq[0][r];
    const float zf = acc[1][r] + xq[1][r];
    const float zg = acc[2][r] + xq[2][r];
    const float zo = acc[3][r] + xq[3][r];
    const float gi = fast_sigmoid(zi), gf = fast_sigmoid(zf);
    const float gg = fast_tanh(zg), go = fast_sigmoid(zo);
    cq[r] = gf * cq[r] + gi * gg;
    h[r] = go * fast_tanh(cq[r]);
  }
}

template <int Q>
__device__ __forceinline__ void r0_pass(
    const short8 (&wf)[10][8], const short8 (&gA)[8], const short8 (&gB)[8],
    const u16* hrow, const u16* lw0, int l, int G, int wid, bool active, int b,
    const float* xwrow, u16 (*hnxt)[296], u64* pub0, int t, f32x4& cq) {
  const int d0 = wid * 64 + Q * 16 + G * 4;
  f32x4 xq[4];
#pragma unroll
  for (int m = 0; m < 4; ++m) xq[m] = *(const f32x4*)(xwrow + m * 256 + d0);
  f32x4 acc[4];
#pragma unroll
  for (int m = 0; m < 4; ++m) acc[m] = f32x4{0.f, 0.f, 0.f, 0.f};
  pass_mfma<Q>(wf, gA, gB, hrow, lw0, l, acc);
  if (active) {
    f32x4 h;
    gates4(acc, xq, cq, h);
    const u32 lo = (u32)f2bf(h[0]) | ((u32)f2bf(h[1]) << 16);
    const u32 hi = (u32)f2bf(h[2]) | ((u32)f2bf(h[3]) << 16);
    *(u32*)&hnxt[b][d0] = lo;
    *(u32*)&hnxt[b][d0 + 2] = hi;
    const size_t j0 = (size_t)t * 512 + b * 128 + (d0 >> 1);
    const u64 tag = ((u64)(u32)(t + 1)) << 32;
    __hip_atomic_store(pub0 + j0, (u64)lo | tag, __ATOMIC_RELAXED, __HIP_MEMORY_SCOPE_AGENT);
    __hip_atomic_store(pub0 + j0 + 1, (u64)hi | tag, __ATOMIC_RELAXED, __HIP_MEMORY_SCOPE_AGENT);
  }
}

template <int Q>
__device__ __forceinline__ void r1_pass(
    const short8 (&wf)[10][8], const short8 (&gA)[8], const short8 (&gB)[8],
    const u16* hrow, const u16* lw0, int l, int G, int wid, bool active, int b,
    const float* bias1s, u64* pub1, int t) {
  const int d0 = wid * 64 + Q * 16 + G * 4;
  f32x4 bq[4];
#pragma unroll
  for (int m = 0; m < 4; ++m) bq[m] = *(const f32x4*)(bias1s + m * 256 + d0);
  f32x4 acc[4];
#pragma unroll
  for (int m = 0; m < 4; ++m) acc[m] = f32x4{0.f, 0.f, 0.f, 0.f};
  pass_mfma<Q>(wf, gA, gB, hrow, lw0, l, acc);
  if (active) {
    const u64 tag = ((u64)(u32)(t + 1)) << 32;
#pragma unroll
    for (int m = 0; m < 4; ++m)
#pragma unroll
      for (int r = 0; r < 4; ++r) {
        const float z = acc[m][r] + bq[m][r];
        __hip_atomic_store(pub1 + (size_t)t * 4096 + b * 1024 + (m * 256 + d0 + r),
                           (u64)__float_as_uint(z) | tag, __ATOMIC_RELAXED,
                           __HIP_MEMORY_SCOPE_AGENT);
      }
  }
}

template <int Q>
__device__ __forceinline__ void r2_pass(
    const short8 (&wf)[10][8], const short8 (&gA)[8], const short8 (&gB)[8],
    const u16* hrow, const u16* lw0, int l, int G, int wid, bool active, int b,
    int beff, const float* xwb, u16 (*hnxt)[296], float* hs1, int t, f32x4& cq) {
  const int d0 = wid * 64 + Q * 16 + G * 4;
  f32x4 xq[4];
#pragma unroll
  for (int m = 0; m < 4; ++m) xq[m] = *(const f32x4*)(xwb + (size_t)beff * 1028 + m * 256 + d0);
  f32x4 acc[4];
#pragma unroll
  for (int m = 0; m < 4; ++m) acc[m] = f32x4{0.f, 0.f, 0.f, 0.f};
  pass_mfma<Q>(wf, gA, gB, hrow, lw0, l, acc);
  if (active) {
    f32x4 h;
    gates4(acc, xq, cq, h);
    const u32 lo = (u32)f2bf(h[0]) | ((u32)f2bf(h[1]) << 16);
    const u32 hi = (u32)f2bf(h[2]) | ((u32)f2bf(h[3]) << 16);
    *(u32*)&hnxt[b][d0] = lo;
    *(u32*)&hnxt[b][d0 + 2] = hi;
    *(float4*)(hs1 + ((size_t)b * 512 + t) * 256 + d0) = make_float4(h[0], h[1], h[2], h[3]);
  }
}

// ------------------------------------------------------------- 3-WG LSTM
__global__ __launch_bounds__(256, 1) void lstm3(
    const float* __restrict__ xw0, const u16* __restrict__ pk,
    const float* __restrict__ bias1s, float* __restrict__ hs1,
    u64* __restrict__ pub0, u64* __restrict__ pub1) {
  __shared__ u16 ldsW[16][8][512];   // 128 KB: 16 weight tiles (frag layout)
  __shared__ u16 hbuf[2][4][296];    // h (bf16), dbuf, padded rows
  __shared__ float xwbuf[4][1028];   // staged xw1 (role 2)

  const int role = blockIdx.x;  // 0: layer0, 1: xw1 streamer, 2: layer1
  const int tid = threadIdx.x;
  const int wid = tid >> 6, l = tid & 63;
  const int row16 = l & 15, G = l >> 4;
  const bool active = (row16 < 4);
  const int b = row16;
  const int beff = active ? b : 3;
  const u16* pkm = pk + (size_t)role * 262144;
  const u16* lw0 = &ldsW[wid * 4][0][0];

  // zero hbuf
  for (int i = tid; i < 2 * 4 * 296; i += 256) ((u16*)hbuf)[i] = 0;
  // fill LDS weight tiles (ti = w*16 + 10 + li)
  for (int u = tid; u < 8192; u += 256) {
    const int slot = u >> 9, kk = (u >> 6) & 7, ll = u & 63;
    const int ti = (slot >> 2) * 16 + 10 + (slot & 3);
    *(short8*)&ldsW[slot][kk][ll * 8] =
        *(const short8*)(pkm + (size_t)(ti * 8 + kk) * 512 + ll * 8);
  }
  // register tiles (ti = wid*16 + 0..9)
  short8 wf[10][8];
#pragma unroll
  for (int i = 0; i < 10; ++i)
#pragma unroll
    for (int kk = 0; kk < 8; ++kk)
      wf[i][kk] = *(const short8*)(pkm + (size_t)((wid * 16 + i) * 8 + kk) * 512 + l * 8);
  __syncthreads();

  if (role == 0) {
    f32x4 cst[4];
#pragma unroll
    for (int q = 0; q < 4; ++q) cst[q] = f32x4{0.f, 0.f, 0.f, 0.f};
    for (int t = 0; t < SEQ; ++t) {
      const int cur = t & 1, nxt = cur ^ 1;
      short8 gA[8], gB[8];
#pragma unroll
      for (int kk = 0; kk < 8; ++kk) {
        gA[kk] = *(const short8*)(pkm + (size_t)((wid * 16 + 14) * 8 + kk) * 512 + l * 8);
        gB[kk] = *(const short8*)(pkm + (size_t)((wid * 16 + 15) * 8 + kk) * 512 + l * 8);
      }
      const u16* hrow = &hbuf[cur][beff][0];
      const float* xwrow = xw0 + ((size_t)beff * 512 + t) * 1024;
      r0_pass<0>(wf, gA, gB, hrow, lw0, l, G, wid, active, b, xwrow, hbuf[nxt], pub0, t, cst[0]);
      r0_pass<1>(wf, gA, gB, hrow, lw0, l, G, wid, active, b, xwrow, hbuf[nxt], pub0, t, cst[1]);
      r0_pass<2>(wf, gA, gB, hrow, lw0, l, G, wid, active, b, xwrow, hbuf[nxt], pub0, t, cst[2]);
      r0_pass<3>(wf, gA, gB, hrow, lw0, l, G, wid, active, b, xwrow, hbuf[nxt], pub0, t, cst[3]);
      __syncthreads();
    }
  } else if (role == 1) {
    for (int t = 0; t < SEQ; ++t) {
      const int cur = t & 1;
      short8 gA[8], gB[8];
#pragma unroll
      for (int kk = 0; kk < 8; ++kk) {
        gA[kk] = *(const short8*)(pkm + (size_t)((wid * 16 + 14) * 8 + kk) * 512 + l * 8);
        gB[kk] = *(const short8*)(pkm + (size_t)((wid * 16 + 15) * 8 + kk) * 512 + l * 8);
      }
      // stage h0(t): 2 tagged words per thread
      const size_t pb = (size_t)t * 512 + (size_t)tid * 2;
      u64 v0 = __hip_atomic_load(pub0 + pb, __ATOMIC_RELAXED, __HIP_MEMORY_SCOPE_AGENT);
      u64 v1 = __hip_atomic_load(pub0 + pb + 1, __ATOMIC_RELAXED, __HIP_MEMORY_SCOPE_AGENT);
      while ((u32)(v0 >> 32) != (u32)(t + 1))
        v0 = __hip_atomic_load(pub0 + pb, __ATOMIC_RELAXED, __HIP_MEMORY_SCOPE_AGENT);
      while ((u32)(v1 >> 32) != (u32)(t + 1))
        v1 = __hip_atomic_load(pub0 + pb + 1, __ATOMIC_RELAXED, __HIP_MEMORY_SCOPE_AGENT);
      const int j0 = tid * 2;
      *(u32*)&hbuf[cur][j0 >> 7][(j0 & 127) * 2] = (u32)v0;
      *(u32*)&hbuf[cur][(j0 + 1) >> 7][((j0 + 1) & 127) * 2] = (u32)v1;
      __syncthreads();
      const u16* hrow = &hbuf[cur][beff][0];
      r1_pass<0>(wf, gA, gB, hrow, lw0, l, G, wid, active, b, bias1s, pub1, t);
      r1_pass<1>(wf, gA, gB, hrow, lw0, l, G, wid, active, b, bias1s, pub1, t);
      r1_pass<2>(wf, gA, gB, hrow, lw0, l, G, wid, active, b, bias1s, pub1, t);
      r1_pass<3>(wf, gA, gB, hrow, lw0, l, G, wid, active, b, bias1s, pub1, t);
    }
  } else {
    f32x4 cst[4];
#pragma unroll
    for (int q = 0; q < 4; ++q) cst[q] = f32x4{0.f, 0.f, 0.f, 0.f};
    for (int t = 0; t < SEQ; ++t) {
      const int cur = t & 1, nxt = cur ^ 1;
      short8 gA[8], gB[8];
#pragma unroll
      for (int kk = 0; kk < 8; ++kk) {
        gA[kk] = *(const short8*)(pkm + (size_t)((wid * 16 + 14) * 8 + kk) * 512 + l * 8);
        gB[kk] = *(const short8*)(pkm + (size_t)((wid * 16 + 15) * 8 + kk) * 512 + l * 8);
      }
      // stage xw1(t): 16 tagged words per thread (issue all, then validate)
      u64 v[16];
#pragma unroll
      for (int s = 0; s < 16; ++s)
        v[s] = __hip_atomic_load(pub1 + (size_t)t * 4096 + s * 256 + tid,
                                 __ATOMIC_RELAXED, __HIP_MEMORY_SCOPE_AGENT);
#pragma unroll
      for (int s = 0; s < 16; ++s)
        while ((u32)(v[s] >> 32) != (u32)(t + 1))
          v[s] = __hip_atomic_load(pub1 + (size_t)t * 4096 + s * 256 + tid,
                                   __ATOMIC_RELAXED, __HIP_MEMORY_SCOPE_AGENT);
#pragma unroll
      for (int s = 0; s < 16; ++s) {
        const int j = s * 256 + tid;
        xwbuf[j >> 10][j & 1023] = __uint_as_float((u32)v[s]);
      }
      __syncthreads();
      const u16* hrow = &hbuf[cur][beff][0];
      r2_pass<0>(wf, gA, gB, hrow, lw0, l, G, wid, active, b, beff, &xwbuf[0][0], hbuf[nxt], hs1, t, cst[0]);
      r2_pass<1>(wf, gA, gB, hrow, lw0, l, G, wid, active, b, beff, &xwbuf[0][0], hbuf[nxt], hs1, t, cst[1]);
      r2_pass<2>(wf, gA, gB, hrow, lw0, l, G, wid, active, b, beff, &xwbuf[0][0], hbuf[nxt], hs1, t, cst[2]);
      r2_pass<3>(wf, gA, gB, hrow, lw0, l, G, wid, active, b, beff, &xwbuf[0][0], hbuf[nxt], hs1, t, cst[3]);
      __syncthreads();
    }
  }
}

// ------------------------------------------------- head: stats = h @ w_lin^T + b
__global__ __launch_bounds__(256) void head_stats(
    const float* __restrict__ hs1, const float* __restrict__ wlin,
    const float* __restrict__ blin, float* __restrict__ mu_out,
    float* __restrict__ sd_out) {
  __shared__ float hsm[4][HD];
  const int blk = blockIdx.x, tid = threadIdx.x;
  const int row0 = blk * 4;
  for (int i = tid; i < 4 * HD; i += 256) hsm[i >> 8][i & 255] = hs1[(size_t)row0 * HD + i];
  __syncthreads();
  const float4* wsd = (const float4*)(wlin + (size_t)tid * HD);
  const float4* wmu = (const float4*)(wlin + (size_t)(HD + tid) * HD);
  float asd[4] = {0, 0, 0, 0}, amu[4] = {0, 0, 0, 0};
#pragma unroll 4
  for (int kc = 0; kc < 64; ++kc) {
    const float4 ws = wsd[kc], wm = wmu[kc];
#pragma unroll
    for (int tt = 0; tt < 4; ++tt) {
      const float4 hv = ((const float4*)hsm[tt])[kc];
      asd[tt] += ws.x * hv.x + ws.y * hv.y + ws.z * hv.z + ws.w * hv.w;
      amu[tt] += wm.x * hv.x + wm.y * hv.y + wm.z * hv.z + wm.w * hv.w;
    }
  }
  const float bsd = blin[tid], bmu = blin[HD + tid];
#pragma unroll
  for (int tt = 0; tt < 4; ++tt) {
    const float zs = asd[tt] + bsd;
    const float sp = (zs > 15.f) ? zs : __logf(1.f + __expf(zs));  // softplus
    sd_out[(size_t)(row0 + tt) * HD + tid] = sp;
    mu_out[(size_t)(row0 + tt) * HD + tid] = amu[tt] + bmu;
  }
}

// ---------------------------------- finalize: std_full + sample
__global__ __launch_bounds__(256) void finalize_fill(
    const float* __restrict__ eps, float* __restrict__ out) {
  float* sample = out;       // currently holds softplus(std) temp
  float* mu = out + 524288;
  float* sf = out + 1048576; // [2048][256][256]
  const int row = blockIdx.x;
  const int tid = threadIdx.x;
  __shared__ float sd[HD];
  sd[tid] = sample[(size_t)row * HD + tid];
  __syncthreads();
  float4* dst = (float4*)(sf + (size_t)row * HD * HD);
  const int rr = tid >> 6, m = tid & 63;
#pragma unroll 4
  for (int g = 0; g < 64; ++g) {
    const int r = g * 4 + rr;
    float4 v = make_float4(0.f, 0.f, 0.f, 0.f);
    const int base = m * 4;
    if (r >= base && r < base + 4) ((float*)&v)[r - base] = sd[r];
    dst[(size_t)r * 64 + m] = v;
  }
  const float mu_v = mu[(size_t)row * HD + tid];
  const float e = eps[(size_t)row * HD + tid];
  sample[(size_t)row * HD + tid] = mu_v + sqrtf(sd[tid]) * e;
}

extern "C" void kernel_launch(void* const* d_in, const int* in_sizes, int n_in,
                              void* d_out, int out_size, void* d_ws, size_t ws_size,
                              hipStream_t stream) {
  const float* x     = (const float*)d_in[0];
  const float* eps   = (const float*)d_in[1];
  const float* w_ih0 = (const float*)d_in[2];
  const float* w_hh0 = (const float*)d_in[3];
  const float* b_ih0 = (const float*)d_in[4];
  const float* b_hh0 = (const float*)d_in[5];
  const float* w_ih1 = (const float*)d_in[6];
  const float* w_hh1 = (const float*)d_in[7];
  const float* b_ih1 = (const float*)d_in[8];
  const float* b_hh1 = (const float*)d_in[9];
  const float* w_lin = (const float*)d_in[10];
  const float* b_lin = (const float*)d_in[11];
  float* out = (float*)d_out;

  // Scratch carved from std_full output region (fully rewritten by finalize
  // each call -> tags never stale at launch; replay-safe).
  float* scratch = out + 1048576;
  float* xw0    = scratch;                        // 2,097,152 f32
  float* hs1    = scratch + 2097152;              //   524,288 f32
  u16*   pk     = (u16*)(scratch + 2621440);      //   786,432 bf16
  float* bias1s = scratch + 3014656;              //     1,024 f32
  u64*   pub0   = (u64*)(scratch + 3015936);      // 2 MB tagged words
  u64*   pub1   = (u64*)(scratch + 3540224);      // 16 MB tagged words

  hipLaunchKernelGGL(prep_pack, dim3(3076), dim3(256), 0, stream,
                     w_hh0, w_ih1, w_hh1, b_ih1, b_hh1, pk, bias1s);
  hipLaunchKernelGGL(xw_gemm, dim3(512), dim3(256), 0, stream, x, w_ih0, b_ih0, b_hh0, xw0);
  hipLaunchKernelGGL(lstm3, dim3(3), dim3(256), 0, stream, xw0, pk, bias1s, hs1, pub0, pub1);
  hipLaunchKernelGGL(head_stats, dim3(512), dim3(256), 0, stream, hs1, w_lin, b_lin,
                     out + 524288, out);
  hipLaunchKernelGGL(finalize_fill, dim3(2048), dim3(256), 0, stream, eps, out);
}